// Round 17
// baseline (304.204 us; speedup 1.0000x reference)
//
#include <hip/hip_runtime.h>
#include <math.h>

typedef __bf16 bf16x8 __attribute__((ext_vector_type(8)));
typedef float f32x4 __attribute__((ext_vector_type(4)));
typedef unsigned short us8 __attribute__((ext_vector_type(8)));

#define B_ 2
#define L_ 2048
#define D_ 2048
#define H_ 16
#define DH 128

__device__ __forceinline__ unsigned short f2b(float f) {
  union { float f; unsigned u; } v; v.f = f;
  unsigned u = v.u;
  return (unsigned short)((u + 0x7fffu + ((u >> 16) & 1u)) >> 16);
}
__device__ __forceinline__ float b2f(unsigned short h) {
  union { unsigned u; float f; } v; v.u = ((unsigned)h) << 16;
  return v.f;
}

#define GLD16(g, l) __builtin_amdgcn_global_load_lds(                          \
    (const __attribute__((address_space(1))) void*)(g),                        \
    (__attribute__((address_space(3))) void*)(l), 16, 0, 0)

#define SBAR() __builtin_amdgcn_s_barrier()
#define LGK0() asm volatile("s_waitcnt lgkmcnt(0)")
#define SCB0() __builtin_amdgcn_sched_barrier(0)
#define VMC3() asm volatile("s_waitcnt vmcnt(3)" ::: "memory")
#define VMC0() asm volatile("s_waitcnt vmcnt(0)" ::: "memory")

__device__ __forceinline__ unsigned ldsoff(const void* p) {
  return (unsigned)(unsigned long long)(const __attribute__((address_space(3))) char*)p;
}
__device__ __forceinline__ bf16x8 dsr128(unsigned a) {
  bf16x8 r;
  asm volatile("ds_read_b128 %0, %1" : "=v"(r) : "v"(a));
  return r;
}

// ---------------- fused fp32 -> bf16 convert (3 arrays, 1 launch) ------------
__global__ void f32_to_bf16_3(const float* __restrict__ a, int na4,
                              const float* __restrict__ b, int nb4,
                              const float* __restrict__ c, int nc4,
                              unsigned short* __restrict__ oa,
                              unsigned short* __restrict__ ob,
                              unsigned short* __restrict__ oc) {
  const int total = na4 + nb4 + nc4;
  int i = blockIdx.x * blockDim.x + threadIdx.x;
  const int stride = gridDim.x * blockDim.x;
  for (; i < total; i += stride) {
    const float* src;
    unsigned short* dst;
    int j = i;
    if (j < na4) { src = a; dst = oa; }
    else if (j < na4 + nb4) { j -= na4; src = b; dst = ob; }
    else { j -= na4 + nb4; src = c; dst = oc; }
    const float4 v = ((const float4*)src)[j];
    ushort4 o;
    o.x = f2b(v.x); o.y = f2b(v.y); o.z = f2b(v.z); o.w = f2b(v.w);
    ((ushort4*)dst)[j] = o;
  }
}

// ====== GEMM1 fused: qkv projection + RoPE + head scatter + V fragpack =======
__global__ __launch_bounds__(512, 4)
void gemm_qkv(const unsigned short* __restrict__ A,
              const unsigned short* __restrict__ Bm,
              unsigned short* __restrict__ Qb,
              unsigned short* __restrict__ Kb,
              unsigned short* __restrict__ Vf, int M, int K) {
  __shared__ __align__(16) unsigned short lA[3][128 * 32];
  __shared__ __align__(16) unsigned short lB[3][256 * 32];
  const int tid = threadIdx.x;
  const int w = tid >> 6, lane = tid & 63;
  const int lo = lane & 15, hi = lane >> 4;
  const int mh = w >> 2;
  const int wn = (w & 3) * 64;
  const int GM = M >> 7;
  const int nwg = gridDim.x;
  const int f = blockIdx.x;
  const int v = (f & 7) * (nwg >> 3) + (f >> 3);  // bijective XCD swizzle
  const int bn = v / GM, bm = v % GM;
  const int NT = K >> 5;

  const int srow = tid >> 2;
  const int gs = (tid & 3) ^ ((srow >> 1) & 3);
  auto stA = [&](int buf, int tile) {
    GLD16(A + (long)(bm * 128 + srow) * K + tile * 32 + gs * 8,
          &lA[buf][(tid & ~63) * 8]);
  };
  auto stB = [&](int buf, int u, int tile) {
    GLD16(Bm + (long)(bn * 256 + u * 128 + srow) * K + tile * 32 + gs * 8,
          &lB[buf][u * 4096 + (tid & ~63) * 8]);
  };

  unsigned aoff[4], boff[4];
#pragma unroll
  for (int mi = 0; mi < 4; ++mi) {
    const int r = mh * 64 + mi * 16 + lo;
    aoff[mi] = ldsoff(&lA[0][0]) + r * 64 + ((hi ^ ((r >> 1) & 3)) * 16);
  }
#pragma unroll
  for (int ni = 0; ni < 4; ++ni) {
    const int rb = wn + ni * 16 + lo;
    boff[ni] = ldsoff(&lB[0][0]) + rb * 64 + ((hi ^ ((rb >> 1) & 3)) * 16);
  }

  f32x4 acc[4][4] = {};

  stA(0, 0); stB(0, 0, 0); stB(0, 1, 0);
  stA(1, 1); stB(1, 0, 1); stB(1, 1, 1);
  VMC3();
  SBAR();

  for (int t = 0; t < NT; ++t) {
    const int bt = t % 3;
    const int b2 = (t + 2) % 3;
    const bool nx = (t + 2 < NT);
    const unsigned ab = (unsigned)(bt * 8192);
    const unsigned bb = (unsigned)(bt * 16384);
    bf16x8 af[4], bfv[4];
#pragma unroll
    for (int mi = 0; mi < 4; ++mi) af[mi] = dsr128(aoff[mi] + ab);
#pragma unroll
    for (int ni = 0; ni < 4; ++ni) bfv[ni] = dsr128(boff[ni] + bb);
    if (nx) { stA(b2, t + 2); stB(b2, 0, t + 2); stB(b2, 1, t + 2); }
    LGK0(); SCB0();
    __builtin_amdgcn_s_setprio(1);
#pragma unroll
    for (int mi = 0; mi < 4; ++mi)
#pragma unroll
      for (int ni = 0; ni < 4; ++ni)
        acc[mi][ni] = __builtin_amdgcn_mfma_f32_16x16x32_bf16(
            af[mi], bfv[ni], acc[mi][ni], 0, 0, 0);
    __builtin_amdgcn_s_setprio(0);
    if (t < NT - 2) VMC3(); else VMC0();
    SBAR();
  }

  // ---------------- fused epilogue ----------------
  const int r0 = bm * 128 + mh * 64;
  const int h = (bn & 7) * 2 + (wn >> 7);
  const int d0 = wn & 64;
  if (bn < 16) {
    unsigned short* dst = (bn < 8) ? Qb : Kb;
    const float sc = (bn < 8) ? 0.12751743f : 1.0f;  // log2(e)/sqrt(128)
#pragma unroll
    for (int ni = 0; ni < 4; ++ni) {
      const int d = d0 + ni * 16 + lo;
      const float invr = exp2f(-(float)(d >> 1) * 0.20762050593045077f) *
                         0.15915494309189535f;
#pragma unroll
      for (int mi = 0; mi < 4; ++mi) {
#pragma unroll
        for (int r = 0; r < 4; ++r) {
          const int row = r0 + mi * 16 + hi * 4 + r;
          const int b = row >> 11, l = row & (L_ - 1);
          const float rev = __builtin_amdgcn_fractf((float)l * invr);
          const float sn = __builtin_amdgcn_sinf(rev);
          const float cs = __builtin_amdgcn_cosf(rev);
          const float v0 = acc[mi][ni][r] * sc;
          const float vp = __shfl_xor(v0, 1);
          const float ov = (d & 1) ? (v0 * cs + vp * sn)
                                   : (v0 * cs - vp * sn);
          dst[((long)(b * H_ + h) * L_ + l) * DH + d] = f2b(ov);
        }
      }
    }
  } else {
#pragma unroll
    for (int ni = 0; ni < 4; ++ni) {
      const int d = d0 + ni * 16 + lo;
#pragma unroll
      for (int mi = 0; mi < 4; ++mi) {
        const int row0 = r0 + mi * 16 + hi * 4;
        const int b = row0 >> 11, l0 = row0 & (L_ - 1);
        const size_t base =
            (((size_t)(b * H_ + h) * 64 + (l0 >> 5)) * 8 + (d >> 4)) * 512;
        const int fl = (d & 15) + ((l0 >> 3) & 3) * 16;
        ushort4 pk;
        pk.x = f2b(acc[mi][ni][0]);
        pk.y = f2b(acc[mi][ni][1]);
        pk.z = f2b(acc[mi][ni][2]);
        pk.w = f2b(acc[mi][ni][3]);
        *(ushort4*)&Vf[base + fl * 8 + (l0 & 7)] = pk;
      }
    }
  }
}

// ================= 128x256 GEMM, BK=32, triple-buffered (GEMM2) ==============
template <bool OUT_BF16>
__global__ __launch_bounds__(512, 4)
void gemmk32(const unsigned short* __restrict__ A,
             const unsigned short* __restrict__ Bm,
             void* __restrict__ Cv, int M, int N, int K) {
  __shared__ __align__(16) unsigned short lA[3][128 * 32];
  __shared__ __align__(16) unsigned short lB[3][256 * 32];
  const int tid = threadIdx.x;
  const int w = tid >> 6, lane = tid & 63;
  const int lo = lane & 15, hi = lane >> 4;
  const int mh = w >> 2;
  const int wn = (w & 3) * 64;
  const int GM = M >> 7;
  const int nwg = gridDim.x;
  const int f = blockIdx.x;
  const int v = (f & 7) * (nwg >> 3) + (f >> 3);
  const int bn = v / GM, bm = v % GM;
  const int NT = K >> 5;

  const int srow = tid >> 2;
  const int gs = (tid & 3) ^ ((srow >> 1) & 3);
  auto stA = [&](int buf, int tile) {
    GLD16(A + (long)(bm * 128 + srow) * K + tile * 32 + gs * 8,
          &lA[buf][(tid & ~63) * 8]);
  };
  auto stB = [&](int buf, int u, int tile) {
    GLD16(Bm + (long)(bn * 256 + u * 128 + srow) * K + tile * 32 + gs * 8,
          &lB[buf][u * 4096 + (tid & ~63) * 8]);
  };

  unsigned aoff[4], boff[4];
#pragma unroll
  for (int mi = 0; mi < 4; ++mi) {
    const int r = mh * 64 + mi * 16 + lo;
    aoff[mi] = ldsoff(&lA[0][0]) + r * 64 + ((hi ^ ((r >> 1) & 3)) * 16);
  }
#pragma unroll
  for (int ni = 0; ni < 4; ++ni) {
    const int rb = wn + ni * 16 + lo;
    boff[ni] = ldsoff(&lB[0][0]) + rb * 64 + ((hi ^ ((rb >> 1) & 3)) * 16);
  }

  f32x4 acc[4][4] = {};

  stA(0, 0); stB(0, 0, 0); stB(0, 1, 0);
  stA(1, 1); stB(1, 0, 1); stB(1, 1, 1);
  VMC3();
  SBAR();

  for (int t = 0; t < NT; ++t) {
    const int bt = t % 3;
    const int b2 = (t + 2) % 3;
    const bool nx = (t + 2 < NT);
    const unsigned ab = (unsigned)(bt * 8192);
    const unsigned bb = (unsigned)(bt * 16384);
    bf16x8 af[4], bfv[4];
#pragma unroll
    for (int mi = 0; mi < 4; ++mi) af[mi] = dsr128(aoff[mi] + ab);
#pragma unroll
    for (int ni = 0; ni < 4; ++ni) bfv[ni] = dsr128(boff[ni] + bb);
    if (nx) { stA(b2, t + 2); stB(b2, 0, t + 2); stB(b2, 1, t + 2); }
    LGK0(); SCB0();
    __builtin_amdgcn_s_setprio(1);
#pragma unroll
    for (int mi = 0; mi < 4; ++mi)
#pragma unroll
      for (int ni = 0; ni < 4; ++ni)
        acc[mi][ni] = __builtin_amdgcn_mfma_f32_16x16x32_bf16(
            af[mi], bfv[ni], acc[mi][ni], 0, 0, 0);
    __builtin_amdgcn_s_setprio(0);
    if (t < NT - 2) VMC3(); else VMC0();
    SBAR();
  }

  const int r0 = bm * 128 + mh * 64;
  const int c0 = bn * 256 + wn;
#pragma unroll
  for (int mi = 0; mi < 4; ++mi) {
#pragma unroll
    for (int r = 0; r < 4; ++r) {
      const long row = r0 + mi * 16 + hi * 4 + r;
#pragma unroll
      for (int ni = 0; ni < 4; ++ni) {
        const int col = c0 + ni * 16 + lo;
        if (OUT_BF16)
          ((unsigned short*)Cv)[row * N + col] = f2b(acc[mi][ni][r]);
        else
          ((float*)Cv)[row * N + col] = acc[mi][ni][r];
      }
    }
  }
}

// ---------------- causal flash attention: fold-paired q-tiles, swapped QK^T --
// 2 kv-64 sub-tiles per outer iteration, ONE barrier per outer (halves the
// __syncthreads/vmcnt-drain count). lK[outer parity][inner]; outer o stages
// both halves of outer o+1; per-64 body identical to proven r16 version.
__global__ __launch_bounds__(256, 2)
void flash_attn3(const unsigned short* __restrict__ Q,
                 const unsigned short* __restrict__ Kg,
                 const unsigned short* __restrict__ Vf,
                 unsigned short* __restrict__ Y) {
  const int p = blockIdx.x;  // 0..15
  const int tA = p, tB = (L_ / 64 - 1) - p;
  const int h = blockIdx.y, b = blockIdx.z;
  const int tid = threadIdx.x;
  const int wave = tid >> 6, lane = tid & 63;
  const int lo = lane & 15, hi = lane >> 4;
  const int swz = (lo & 7) << 4;
  const int qA = tA * 64 + wave * 16;
  const int qB = tB * 64 + wave * 16;
  const long hoff = ((long)(b * H_ + h)) * L_ * DH;
  const unsigned short* Qh = Q + hoff;
  const unsigned short* Kh = Kg + hoff;
  const unsigned short* Vfh = Vf + ((size_t)(b * H_ + h)) * (64 * 8 * 512);

  __shared__ unsigned short lK[2][2][64 * 128];
  __shared__ unsigned short pl[4][2][16 * 72];
  unsigned short* plA = &pl[wave][0][0];
  unsigned short* plB = &pl[wave][1][0];

  auto stage = [&](int op, int in, int kv0s) {
    unsigned short* bk = &lK[op][in][0];
#pragma unroll
    for (int j = 0; j < 4; ++j) {
      const int c = j * 256 + tid;
      const int row = c >> 4;
      const int soff = ((c & 15) ^ (row & 7)) << 3;
      GLD16(Kh + (long)(kv0s + row) * DH + soff, &bk[(c & ~63) * 8]);
    }
  };

  bf16x8 qfA[4], qfB[4];
#pragma unroll
  for (int s = 0; s < 4; ++s) {
    qfA[s] = *(const bf16x8*)&Qh[(long)(qA + lo) * DH + s * 32 + hi * 8];
    qfB[s] = *(const bf16x8*)&Qh[(long)(qB + lo) * DH + s * 32 + hi * 8];
  }

  float mA = -INFINITY, lsA = 0.f, mB = -INFINITY, lsB = 0.f;
  f32x4 yA[8] = {}, yB[8] = {};

  auto softmax = [&](f32x4 (&st)[4], float& m, float& lsum, f32x4 (&yacc)[8],
                     unsigned short* plw, int qw, int kv0) {
    if (kv0 + 63 > qw) {
      const int d0 = qw + lo - kv0 - hi * 4;
#pragma unroll
      for (int t = 0; t < 4; ++t) {
        const int dt = d0 - t * 16;
#pragma unroll
        for (int r = 0; r < 4; ++r)
          if (r > dt) st[t][r] = -INFINITY;
      }
    }
    float tm0 = fmaxf(fmaxf(st[0][0], st[0][1]), fmaxf(st[0][2], st[0][3]));
    float tm1 = fmaxf(fmaxf(st[1][0], st[1][1]), fmaxf(st[1][2], st[1][3]));
    float tm2 = fmaxf(fmaxf(st[2][0], st[2][1]), fmaxf(st[2][2], st[2][3]));
    float tm3 = fmaxf(fmaxf(st[3][0], st[3][1]), fmaxf(st[3][2], st[3][3]));
    float rm = fmaxf(fmaxf(tm0, tm1), fmaxf(tm2, tm3));
    rm = fmaxf(rm, __shfl_xor(rm, 16));
    rm = fmaxf(rm, __shfl_xor(rm, 32));
    if (!__all(rm <= m + 8.f)) {
      const float mn = fmaxf(m, rm);
      const float alpha = exp2f(m - mn);
      m = mn;
      lsum *= alpha;
      float ar[4];
#pragma unroll
      for (int r = 0; r < 4; ++r) ar[r] = __shfl(alpha, hi * 4 + r);
#pragma unroll
      for (int t2 = 0; t2 < 8; ++t2)
#pragma unroll
        for (int r = 0; r < 4; ++r) yacc[t2][r] *= ar[r];
    }
    float rs = 0.f;
#pragma unroll
    for (int t = 0; t < 4; ++t) {
#pragma unroll
      for (int r2 = 0; r2 < 2; ++r2) {
        const float e0 = exp2f(st[t][2 * r2] - m);
        const float e1 = exp2f(st[t][2 * r2 + 1] - m);
        rs += e0 + e1;
        const unsigned short u0 = __builtin_bit_cast(unsigned short, (__bf16)e0);
        const unsigned short u1 = __builtin_bit_cast(unsigned short, (__bf16)e1);
        *(unsigned*)&plw[lo * 72 + t * 16 + hi * 4 + 2 * r2] =
            (unsigned)u0 | ((unsigned)u1 << 16);
      }
    }
    rs += __shfl_xor(rs, 16);
    rs += __shfl_xor(rs, 32);
    lsum += rs;
  };

  const int nIt64 = tB + 1;
  const int nOut = (nIt64 + 1) >> 1;
  // prologue: stage outer 0 (both halves, guarded)
  stage(0, 0, 0);
  if (1 < nIt64) stage(0, 1, 64);
  __syncthreads();

  for (int o = 0; o < nOut; ++o) {
    const int op = o & 1;
    // stage outer o+1 (both halves, guarded); WAR-safe: parity-disjoint buffer
    const int b0 = 2 * (o + 1);
    if (b0 < nIt64) stage(op ^ 1, 0, b0 * 64);
    if (b0 + 1 < nIt64) stage(op ^ 1, 1, (b0 + 1) * 64);
#pragma unroll
    for (int in = 0; in < 2; ++in) {
      const int it = 2 * o + in;
      if (it < nIt64) {
        const int kv0 = it * 64;
        const bool aAct = (it <= tA);
        const char* bkc = (const char*)&lK[op][in][0];
        f32x4 stA[4] = {}, stB[4] = {};
        __builtin_amdgcn_s_setprio(1);
        if (aAct) {
#pragma unroll
          for (int s = 0; s < 4; ++s) {
            const int inner = (lo * 256 + s * 64 + hi * 16) ^ swz;
#pragma unroll
            for (int t = 0; t < 4; ++t) {
              const bf16x8 kf = *(const bf16x8*)(bkc + t * 4096 + inner);
              stA[t] = __builtin_amdgcn_mfma_f32_16x16x32_bf16(kf, qfA[s], stA[t], 0, 0, 0);
              stB[t] = __builtin_amdgcn_mfma_f32_16x16x32_bf16(kf, qfB[s], stB[t], 0, 0, 0);
            }
          }
        } else {
#pragma unroll
          for (int s = 0; s < 4; ++s) {
            const int inner = (lo * 256 + s * 64 + hi * 16) ^ swz;
#pragma unroll
            for (int t = 0; t < 4; ++t) {
              const bf16x8 kf = *(const bf16x8*)(bkc + t * 4096 + inner);
              stB[t] = __builtin_amdgcn_mfma_f32_16x16x32_bf16(kf, qfB[s], stB[t], 0, 0, 0);
            }
          }
        }
        __builtin_amdgcn_s_setprio(0);
        // hoisted V-fragment loads: L2 latency overlaps softmax VALU work
        const unsigned short* vbase = Vfh + (size_t)(it * 16) * 512 + lane * 8;
        bf16x8 vf[16];
#pragma unroll
        for (int t2 = 0; t2 < 16; ++t2)
          vf[t2] = *(const bf16x8*)(vbase + (size_t)t2 * 512);
        if (aAct) softmax(stA, mA, lsA, yA, plA, qA, kv0);
        softmax(stB, mB, lsB, yB, plB, qB, kv0);
        __builtin_amdgcn_s_setprio(1);
#pragma unroll
        for (int kt = 0; kt < 2; ++kt) {
          const bf16x8 pfB = *(const bf16x8*)&plB[lo * 72 + kt * 32 + hi * 8];
#pragma unroll
          for (int t2 = 0; t2 < 8; ++t2)
            yB[t2] = __builtin_amdgcn_mfma_f32_16x16x32_bf16(pfB, vf[kt * 8 + t2], yB[t2], 0, 0, 0);
          if (aAct) {
            const bf16x8 pfA = *(const bf16x8*)&plA[lo * 72 + kt * 32 + hi * 8];
#pragma unroll
            for (int t2 = 0; t2 < 8; ++t2)
              yA[t2] = __builtin_amdgcn_mfma_f32_16x16x32_bf16(pfA, vf[kt * 8 + t2], yA[t2], 0, 0, 0);
          }
        }
        __builtin_amdgcn_s_setprio(0);
      }
    }
    __syncthreads();
  }

  auto wout = [&](f32x4 (&yacc)[8], float lsum, int qw) {
    const float inv = 1.f / lsum;
    float ir[4];
#pragma unroll
    for (int r = 0; r < 4; ++r) ir[r] = __shfl(inv, hi * 4 + r);
#pragma unroll
    for (int r = 0; r < 4; ++r) {
      const long row = qw + hi * 4 + r;
      unsigned short* yrow = Y + ((long)b * L_ + row) * D_ + h * DH;
#pragma unroll
      for (int t2 = 0; t2 < 8; ++t2)
        yrow[t2 * 16 + lo] = f2b(yacc[t2][r] * ir[r]);
    }
  };
  wout(yA, lsA, qA);
  wout(yB, lsB, qB);
}

extern "C" void kernel_launch(void* const* d_in, const int* in_sizes, int n_in,
                              void* d_out, int out_size, void* d_ws, size_t ws_size,
                              hipStream_t stream) {
  const float* x = (const float*)d_in[0];
  const float* wqkv = (const float*)d_in[1];
  const float* wo = (const float*)d_in[2];
  float* out = (float*)d_out;

  unsigned short* ws = (unsigned short*)d_ws;
  const size_t N_X = (size_t)B_ * L_ * D_;
  const size_t N_WQKV = (size_t)3 * D_ * D_;
  const size_t N_WO = (size_t)D_ * D_;
  const size_t N_HEAD = (size_t)B_ * H_ * L_ * DH;
  unsigned short* xb = ws;
  unsigned short* wqkb = xb + N_X;
  unsigned short* wob = wqkb + N_WQKV;
  unsigned short* Qb = wob + N_WO;
  unsigned short* Kb = Qb + N_HEAD;
  unsigned short* Vf = Kb + N_HEAD;
  unsigned short* Yb = Vf + N_HEAD;
  const size_t need = (size_t)(Yb + N_HEAD - ws) * sizeof(unsigned short);
  if (ws_size < need) return;

  f32_to_bf16_3<<<2048, 256, 0, stream>>>(
      x, (int)(N_X / 4), wqkv, (int)(N_WQKV / 4), wo, (int)(N_WO / 4),
      xb, wqkb, wob);

  // fused qkv-projection + RoPE + scatter + V-fragpack: 32x24 = 768 blocks
  gemm_qkv<<<(B_ * L_ / 128) * (3 * D_ / 256), 512, 0, stream>>>(
      xb, wqkb, Qb, Kb, Vf, B_ * L_, D_);

  flash_attn3<<<dim3(16, H_, B_), 256, 0, stream>>>(Qb, Kb, Vf, Yb);

  // out = y @ W_o^T : M=4096, N=2048, K=2048 -> 32x8 = 256 blocks
  gemmk32<false><<<(B_ * L_ / 128) * (D_ / 256), 512, 0, stream>>>(
      Yb, wob, out, B_ * L_, D_, D_);
}

// Round 18
// 259.066 us; speedup vs baseline: 1.1742x; 1.1742x over previous
//
#include <hip/hip_runtime.h>
#include <math.h>

typedef __bf16 bf16x8 __attribute__((ext_vector_type(8)));
typedef float f32x4 __attribute__((ext_vector_type(4)));
typedef unsigned short us8 __attribute__((ext_vector_type(8)));

#define B_ 2
#define L_ 2048
#define D_ 2048
#define H_ 16
#define DH 128

__device__ __forceinline__ unsigned short f2b(float f) {
  union { float f; unsigned u; } v; v.f = f;
  unsigned u = v.u;
  return (unsigned short)((u + 0x7fffu + ((u >> 16) & 1u)) >> 16);
}
__device__ __forceinline__ float b2f(unsigned short h) {
  union { unsigned u; float f; } v; v.u = ((unsigned)h) << 16;
  return v.f;
}

#define GLD16(g, l) __builtin_amdgcn_global_load_lds(                          \
    (const __attribute__((address_space(1))) void*)(g),                        \
    (__attribute__((address_space(3))) void*)(l), 16, 0, 0)

#define SBAR() __builtin_amdgcn_s_barrier()
#define LGK0() asm volatile("s_waitcnt lgkmcnt(0)")
#define SCB0() __builtin_amdgcn_sched_barrier(0)
#define VMC3() asm volatile("s_waitcnt vmcnt(3)" ::: "memory")
#define VMC0() asm volatile("s_waitcnt vmcnt(0)" ::: "memory")

__device__ __forceinline__ unsigned ldsoff(const void* p) {
  return (unsigned)(unsigned long long)(const __attribute__((address_space(3))) char*)p;
}
__device__ __forceinline__ bf16x8 dsr128(unsigned a) {
  bf16x8 r;
  asm volatile("ds_read_b128 %0, %1" : "=v"(r) : "v"(a));
  return r;
}

// ---------------- fused fp32 -> bf16 convert (3 arrays, 1 launch) ------------
__global__ void f32_to_bf16_3(const float* __restrict__ a, int na4,
                              const float* __restrict__ b, int nb4,
                              const float* __restrict__ c, int nc4,
                              unsigned short* __restrict__ oa,
                              unsigned short* __restrict__ ob,
                              unsigned short* __restrict__ oc) {
  const int total = na4 + nb4 + nc4;
  int i = blockIdx.x * blockDim.x + threadIdx.x;
  const int stride = gridDim.x * blockDim.x;
  for (; i < total; i += stride) {
    const float* src;
    unsigned short* dst;
    int j = i;
    if (j < na4) { src = a; dst = oa; }
    else if (j < na4 + nb4) { j -= na4; src = b; dst = ob; }
    else { j -= na4 + nb4; src = c; dst = oc; }
    const float4 v = ((const float4*)src)[j];
    ushort4 o;
    o.x = f2b(v.x); o.y = f2b(v.y); o.z = f2b(v.z); o.w = f2b(v.w);
    ((ushort4*)dst)[j] = o;
  }
}

// ====== GEMM1 fused: qkv projection + RoPE + head scatter + V fragpack =======
__global__ __launch_bounds__(512, 4)
void gemm_qkv(const unsigned short* __restrict__ A,
              const unsigned short* __restrict__ Bm,
              unsigned short* __restrict__ Qb,
              unsigned short* __restrict__ Kb,
              unsigned short* __restrict__ Vf, int M, int K) {
  __shared__ __align__(16) unsigned short lA[3][128 * 32];
  __shared__ __align__(16) unsigned short lB[3][256 * 32];
  const int tid = threadIdx.x;
  const int w = tid >> 6, lane = tid & 63;
  const int lo = lane & 15, hi = lane >> 4;
  const int mh = w >> 2;
  const int wn = (w & 3) * 64;
  const int GM = M >> 7;
  const int nwg = gridDim.x;
  const int f = blockIdx.x;
  const int v = (f & 7) * (nwg >> 3) + (f >> 3);  // bijective XCD swizzle
  const int bn = v / GM, bm = v % GM;
  const int NT = K >> 5;

  const int srow = tid >> 2;
  const int gs = (tid & 3) ^ ((srow >> 1) & 3);
  auto stA = [&](int buf, int tile) {
    GLD16(A + (long)(bm * 128 + srow) * K + tile * 32 + gs * 8,
          &lA[buf][(tid & ~63) * 8]);
  };
  auto stB = [&](int buf, int u, int tile) {
    GLD16(Bm + (long)(bn * 256 + u * 128 + srow) * K + tile * 32 + gs * 8,
          &lB[buf][u * 4096 + (tid & ~63) * 8]);
  };

  unsigned aoff[4], boff[4];
#pragma unroll
  for (int mi = 0; mi < 4; ++mi) {
    const int r = mh * 64 + mi * 16 + lo;
    aoff[mi] = ldsoff(&lA[0][0]) + r * 64 + ((hi ^ ((r >> 1) & 3)) * 16);
  }
#pragma unroll
  for (int ni = 0; ni < 4; ++ni) {
    const int rb = wn + ni * 16 + lo;
    boff[ni] = ldsoff(&lB[0][0]) + rb * 64 + ((hi ^ ((rb >> 1) & 3)) * 16);
  }

  f32x4 acc[4][4] = {};

  stA(0, 0); stB(0, 0, 0); stB(0, 1, 0);
  stA(1, 1); stB(1, 0, 1); stB(1, 1, 1);
  VMC3();
  SBAR();

  for (int t = 0; t < NT; ++t) {
    const int bt = t % 3;
    const int b2 = (t + 2) % 3;
    const bool nx = (t + 2 < NT);
    const unsigned ab = (unsigned)(bt * 8192);
    const unsigned bb = (unsigned)(bt * 16384);
    bf16x8 af[4], bfv[4];
#pragma unroll
    for (int mi = 0; mi < 4; ++mi) af[mi] = dsr128(aoff[mi] + ab);
#pragma unroll
    for (int ni = 0; ni < 4; ++ni) bfv[ni] = dsr128(boff[ni] + bb);
    if (nx) { stA(b2, t + 2); stB(b2, 0, t + 2); stB(b2, 1, t + 2); }
    LGK0(); SCB0();
    __builtin_amdgcn_s_setprio(1);
#pragma unroll
    for (int mi = 0; mi < 4; ++mi)
#pragma unroll
      for (int ni = 0; ni < 4; ++ni)
        acc[mi][ni] = __builtin_amdgcn_mfma_f32_16x16x32_bf16(
            af[mi], bfv[ni], acc[mi][ni], 0, 0, 0);
    __builtin_amdgcn_s_setprio(0);
    if (t < NT - 2) VMC3(); else VMC0();
    SBAR();
  }

  // ---------------- fused epilogue ----------------
  const int r0 = bm * 128 + mh * 64;
  const int h = (bn & 7) * 2 + (wn >> 7);
  const int d0 = wn & 64;
  if (bn < 16) {
    unsigned short* dst = (bn < 8) ? Qb : Kb;
    const float sc = (bn < 8) ? 0.12751743f : 1.0f;  // log2(e)/sqrt(128)
#pragma unroll
    for (int ni = 0; ni < 4; ++ni) {
      const int d = d0 + ni * 16 + lo;
      const float invr = exp2f(-(float)(d >> 1) * 0.20762050593045077f) *
                         0.15915494309189535f;
#pragma unroll
      for (int mi = 0; mi < 4; ++mi) {
#pragma unroll
        for (int r = 0; r < 4; ++r) {
          const int row = r0 + mi * 16 + hi * 4 + r;
          const int b = row >> 11, l = row & (L_ - 1);
          const float rev = __builtin_amdgcn_fractf((float)l * invr);
          const float sn = __builtin_amdgcn_sinf(rev);
          const float cs = __builtin_amdgcn_cosf(rev);
          const float v0 = acc[mi][ni][r] * sc;
          const float vp = __shfl_xor(v0, 1);
          const float ov = (d & 1) ? (v0 * cs + vp * sn)
                                   : (v0 * cs - vp * sn);
          dst[((long)(b * H_ + h) * L_ + l) * DH + d] = f2b(ov);
        }
      }
    }
  } else {
#pragma unroll
    for (int ni = 0; ni < 4; ++ni) {
      const int d = d0 + ni * 16 + lo;
#pragma unroll
      for (int mi = 0; mi < 4; ++mi) {
        const int row0 = r0 + mi * 16 + hi * 4;
        const int b = row0 >> 11, l0 = row0 & (L_ - 1);
        const size_t base =
            (((size_t)(b * H_ + h) * 64 + (l0 >> 5)) * 8 + (d >> 4)) * 512;
        const int fl = (d & 15) + ((l0 >> 3) & 3) * 16;
        ushort4 pk;
        pk.x = f2b(acc[mi][ni][0]);
        pk.y = f2b(acc[mi][ni][1]);
        pk.z = f2b(acc[mi][ni][2]);
        pk.w = f2b(acc[mi][ni][3]);
        *(ushort4*)&Vf[base + fl * 8 + (l0 & 7)] = pk;
      }
    }
  }
}

// ================= 128x256 GEMM, BK=32, triple-buffered (GEMM2) ==============
template <bool OUT_BF16>
__global__ __launch_bounds__(512, 4)
void gemmk32(const unsigned short* __restrict__ A,
             const unsigned short* __restrict__ Bm,
             void* __restrict__ Cv, int M, int N, int K) {
  __shared__ __align__(16) unsigned short lA[3][128 * 32];
  __shared__ __align__(16) unsigned short lB[3][256 * 32];
  const int tid = threadIdx.x;
  const int w = tid >> 6, lane = tid & 63;
  const int lo = lane & 15, hi = lane >> 4;
  const int mh = w >> 2;
  const int wn = (w & 3) * 64;
  const int GM = M >> 7;
  const int nwg = gridDim.x;
  const int f = blockIdx.x;
  const int v = (f & 7) * (nwg >> 3) + (f >> 3);
  const int bn = v / GM, bm = v % GM;
  const int NT = K >> 5;

  const int srow = tid >> 2;
  const int gs = (tid & 3) ^ ((srow >> 1) & 3);
  auto stA = [&](int buf, int tile) {
    GLD16(A + (long)(bm * 128 + srow) * K + tile * 32 + gs * 8,
          &lA[buf][(tid & ~63) * 8]);
  };
  auto stB = [&](int buf, int u, int tile) {
    GLD16(Bm + (long)(bn * 256 + u * 128 + srow) * K + tile * 32 + gs * 8,
          &lB[buf][u * 4096 + (tid & ~63) * 8]);
  };

  unsigned aoff[4], boff[4];
#pragma unroll
  for (int mi = 0; mi < 4; ++mi) {
    const int r = mh * 64 + mi * 16 + lo;
    aoff[mi] = ldsoff(&lA[0][0]) + r * 64 + ((hi ^ ((r >> 1) & 3)) * 16);
  }
#pragma unroll
  for (int ni = 0; ni < 4; ++ni) {
    const int rb = wn + ni * 16 + lo;
    boff[ni] = ldsoff(&lB[0][0]) + rb * 64 + ((hi ^ ((rb >> 1) & 3)) * 16);
  }

  f32x4 acc[4][4] = {};

  stA(0, 0); stB(0, 0, 0); stB(0, 1, 0);
  stA(1, 1); stB(1, 0, 1); stB(1, 1, 1);
  VMC3();
  SBAR();

  for (int t = 0; t < NT; ++t) {
    const int bt = t % 3;
    const int b2 = (t + 2) % 3;
    const bool nx = (t + 2 < NT);
    const unsigned ab = (unsigned)(bt * 8192);
    const unsigned bb = (unsigned)(bt * 16384);
    bf16x8 af[4], bfv[4];
#pragma unroll
    for (int mi = 0; mi < 4; ++mi) af[mi] = dsr128(aoff[mi] + ab);
#pragma unroll
    for (int ni = 0; ni < 4; ++ni) bfv[ni] = dsr128(boff[ni] + bb);
    if (nx) { stA(b2, t + 2); stB(b2, 0, t + 2); stB(b2, 1, t + 2); }
    LGK0(); SCB0();
    __builtin_amdgcn_s_setprio(1);
#pragma unroll
    for (int mi = 0; mi < 4; ++mi)
#pragma unroll
      for (int ni = 0; ni < 4; ++ni)
        acc[mi][ni] = __builtin_amdgcn_mfma_f32_16x16x32_bf16(
            af[mi], bfv[ni], acc[mi][ni], 0, 0, 0);
    __builtin_amdgcn_s_setprio(0);
    if (t < NT - 2) VMC3(); else VMC0();
    SBAR();
  }

  const int r0 = bm * 128 + mh * 64;
  const int c0 = bn * 256 + wn;
#pragma unroll
  for (int mi = 0; mi < 4; ++mi) {
#pragma unroll
    for (int r = 0; r < 4; ++r) {
      const long row = r0 + mi * 16 + hi * 4 + r;
#pragma unroll
      for (int ni = 0; ni < 4; ++ni) {
        const int col = c0 + ni * 16 + lo;
        if (OUT_BF16)
          ((unsigned short*)Cv)[row * N + col] = f2b(acc[mi][ni][r]);
        else
          ((float*)Cv)[row * N + col] = acc[mi][ni][r];
      }
    }
  }
}

// ---------------- causal flash attention: fold-paired q-tiles, swapped QK^T --
// (r16 proven config: lK[2] dbuf 74KB total LDS -> 2 blocks/CU)
__global__ __launch_bounds__(256, 2)
void flash_attn3(const unsigned short* __restrict__ Q,
                 const unsigned short* __restrict__ Kg,
                 const unsigned short* __restrict__ Vf,
                 unsigned short* __restrict__ Y) {
  const int p = blockIdx.x;  // 0..15
  const int tA = p, tB = (L_ / 64 - 1) - p;
  const int h = blockIdx.y, b = blockIdx.z;
  const int tid = threadIdx.x;
  const int wave = tid >> 6, lane = tid & 63;
  const int lo = lane & 15, hi = lane >> 4;
  const int swz = (lo & 7) << 4;
  const int qA = tA * 64 + wave * 16;
  const int qB = tB * 64 + wave * 16;
  const long hoff = ((long)(b * H_ + h)) * L_ * DH;
  const unsigned short* Qh = Q + hoff;
  const unsigned short* Kh = Kg + hoff;
  const unsigned short* Vfh = Vf + ((size_t)(b * H_ + h)) * (64 * 8 * 512);

  __shared__ unsigned short lK[2][64 * 128];
  __shared__ unsigned short pl[4][2][16 * 72];
  unsigned short* plA = &pl[wave][0][0];
  unsigned short* plB = &pl[wave][1][0];

  auto stage = [&](int bufi, int kv0s) {
    unsigned short* bk = &lK[bufi][0];
#pragma unroll
    for (int j = 0; j < 4; ++j) {
      const int c = j * 256 + tid;
      const int row = c >> 4;
      const int soff = ((c & 15) ^ (row & 7)) << 3;
      GLD16(Kh + (long)(kv0s + row) * DH + soff, &bk[(c & ~63) * 8]);
    }
  };

  bf16x8 qfA[4], qfB[4];
#pragma unroll
  for (int s = 0; s < 4; ++s) {
    qfA[s] = *(const bf16x8*)&Qh[(long)(qA + lo) * DH + s * 32 + hi * 8];
    qfB[s] = *(const bf16x8*)&Qh[(long)(qB + lo) * DH + s * 32 + hi * 8];
  }

  float mA = -INFINITY, lsA = 0.f, mB = -INFINITY, lsB = 0.f;
  f32x4 yA[8] = {}, yB[8] = {};

  auto softmax = [&](f32x4 (&st)[4], float& m, float& lsum, f32x4 (&yacc)[8],
                     unsigned short* plw, int qw, int kv0) {
    if (kv0 + 63 > qw) {
      const int d0 = qw + lo - kv0 - hi * 4;
#pragma unroll
      for (int t = 0; t < 4; ++t) {
        const int dt = d0 - t * 16;
#pragma unroll
        for (int r = 0; r < 4; ++r)
          if (r > dt) st[t][r] = -INFINITY;
      }
    }
    float tm0 = fmaxf(fmaxf(st[0][0], st[0][1]), fmaxf(st[0][2], st[0][3]));
    float tm1 = fmaxf(fmaxf(st[1][0], st[1][1]), fmaxf(st[1][2], st[1][3]));
    float tm2 = fmaxf(fmaxf(st[2][0], st[2][1]), fmaxf(st[2][2], st[2][3]));
    float tm3 = fmaxf(fmaxf(st[3][0], st[3][1]), fmaxf(st[3][2], st[3][3]));
    float rm = fmaxf(fmaxf(tm0, tm1), fmaxf(tm2, tm3));
    rm = fmaxf(rm, __shfl_xor(rm, 16));
    rm = fmaxf(rm, __shfl_xor(rm, 32));
    if (!__all(rm <= m + 8.f)) {
      const float mn = fmaxf(m, rm);
      const float alpha = exp2f(m - mn);
      m = mn;
      lsum *= alpha;
      float ar[4];
#pragma unroll
      for (int r = 0; r < 4; ++r) ar[r] = __shfl(alpha, hi * 4 + r);
#pragma unroll
      for (int t2 = 0; t2 < 8; ++t2)
#pragma unroll
        for (int r = 0; r < 4; ++r) yacc[t2][r] *= ar[r];
    }
    float rs = 0.f;
#pragma unroll
    for (int t = 0; t < 4; ++t) {
#pragma unroll
      for (int r2 = 0; r2 < 2; ++r2) {
        const float e0 = exp2f(st[t][2 * r2] - m);
        const float e1 = exp2f(st[t][2 * r2 + 1] - m);
        rs += e0 + e1;
        const unsigned short u0 = __builtin_bit_cast(unsigned short, (__bf16)e0);
        const unsigned short u1 = __builtin_bit_cast(unsigned short, (__bf16)e1);
        *(unsigned*)&plw[lo * 72 + t * 16 + hi * 4 + 2 * r2] =
            (unsigned)u0 | ((unsigned)u1 << 16);
      }
    }
    rs += __shfl_xor(rs, 16);
    rs += __shfl_xor(rs, 32);
    lsum += rs;
  };

  const int nIter = tB + 1;
  stage(0, 0);
  __syncthreads();

  for (int it = 0; it < nIter; ++it) {
    const int kv0 = it * 64;
    const bool aAct = (it <= tA);
    if (it + 1 < nIter) stage((it + 1) & 1, kv0 + 64);
    const char* bkc = (const char*)&lK[it & 1][0];
    f32x4 stA[4] = {}, stB[4] = {};
    __builtin_amdgcn_s_setprio(1);
    if (aAct) {
#pragma unroll
      for (int s = 0; s < 4; ++s) {
        const int inner = (lo * 256 + s * 64 + hi * 16) ^ swz;
#pragma unroll
        for (int t = 0; t < 4; ++t) {
          const bf16x8 kf = *(const bf16x8*)(bkc + t * 4096 + inner);
          stA[t] = __builtin_amdgcn_mfma_f32_16x16x32_bf16(kf, qfA[s], stA[t], 0, 0, 0);
          stB[t] = __builtin_amdgcn_mfma_f32_16x16x32_bf16(kf, qfB[s], stB[t], 0, 0, 0);
        }
      }
    } else {
#pragma unroll
      for (int s = 0; s < 4; ++s) {
        const int inner = (lo * 256 + s * 64 + hi * 16) ^ swz;
#pragma unroll
        for (int t = 0; t < 4; ++t) {
          const bf16x8 kf = *(const bf16x8*)(bkc + t * 4096 + inner);
          stB[t] = __builtin_amdgcn_mfma_f32_16x16x32_bf16(kf, qfB[s], stB[t], 0, 0, 0);
        }
      }
    }
    __builtin_amdgcn_s_setprio(0);
    // hoisted V-fragment loads: L2 latency overlaps softmax VALU work
    const unsigned short* vbase = Vfh + (size_t)(it * 16) * 512 + lane * 8;
    bf16x8 vf[16];
#pragma unroll
    for (int t2 = 0; t2 < 16; ++t2)
      vf[t2] = *(const bf16x8*)(vbase + (size_t)t2 * 512);
    if (aAct) softmax(stA, mA, lsA, yA, plA, qA, kv0);
    softmax(stB, mB, lsB, yB, plB, qB, kv0);
    __builtin_amdgcn_s_setprio(1);
#pragma unroll
    for (int kt = 0; kt < 2; ++kt) {
      const bf16x8 pfB = *(const bf16x8*)&plB[lo * 72 + kt * 32 + hi * 8];
#pragma unroll
      for (int t2 = 0; t2 < 8; ++t2)
        yB[t2] = __builtin_amdgcn_mfma_f32_16x16x32_bf16(pfB, vf[kt * 8 + t2], yB[t2], 0, 0, 0);
      if (aAct) {
        const bf16x8 pfA = *(const bf16x8*)&plA[lo * 72 + kt * 32 + hi * 8];
#pragma unroll
        for (int t2 = 0; t2 < 8; ++t2)
          yA[t2] = __builtin_amdgcn_mfma_f32_16x16x32_bf16(pfA, vf[kt * 8 + t2], yA[t2], 0, 0, 0);
      }
    }
    __builtin_amdgcn_s_setprio(0);
    __syncthreads();
  }

  auto wout = [&](f32x4 (&yacc)[8], float lsum, int qw) {
    const float inv = 1.f / lsum;
    float ir[4];
#pragma unroll
    for (int r = 0; r < 4; ++r) ir[r] = __shfl(inv, hi * 4 + r);
#pragma unroll
    for (int r = 0; r < 4; ++r) {
      const long row = qw + hi * 4 + r;
      unsigned short* yrow = Y + ((long)b * L_ + row) * D_ + h * DH;
#pragma unroll
      for (int t2 = 0; t2 < 8; ++t2)
        yrow[t2 * 16 + lo] = f2b(yacc[t2][r] * ir[r]);
    }
  };
  wout(yA, lsA, qA);
  wout(yB, lsB, qB);
}

extern "C" void kernel_launch(void* const* d_in, const int* in_sizes, int n_in,
                              void* d_out, int out_size, void* d_ws, size_t ws_size,
                              hipStream_t stream) {
  const float* x = (const float*)d_in[0];
  const float* wqkv = (const float*)d_in[1];
  const float* wo = (const float*)d_in[2];
  float* out = (float*)d_out;

  unsigned short* ws = (unsigned short*)d_ws;
  const size_t N_X = (size_t)B_ * L_ * D_;
  const size_t N_WQKV = (size_t)3 * D_ * D_;
  const size_t N_WO = (size_t)D_ * D_;
  const size_t N_HEAD = (size_t)B_ * H_ * L_ * DH;
  unsigned short* xb = ws;
  unsigned short* wqkb = xb + N_X;
  unsigned short* wob = wqkb + N_WQKV;
  unsigned short* Qb = wob + N_WO;
  unsigned short* Kb = Qb + N_HEAD;
  unsigned short* Vf = Kb + N_HEAD;
  unsigned short* Yb = Vf + N_HEAD;
  const size_t need = (size_t)(Yb + N_HEAD - ws) * sizeof(unsigned short);
  if (ws_size < need) return;

  f32_to_bf16_3<<<2048, 256, 0, stream>>>(
      x, (int)(N_X / 4), wqkv, (int)(N_WQKV / 4), wo, (int)(N_WO / 4),
      xb, wqkb, wob);

  // fused qkv-projection + RoPE + scatter + V-fragpack: 32x24 = 768 blocks
  gemm_qkv<<<(B_ * L_ / 128) * (3 * D_ / 256), 512, 0, stream>>>(
      xb, wqkb, Qb, Kb, Vf, B_ * L_, D_);

  flash_attn3<<<dim3(16, H_, B_), 256, 0, stream>>>(Qb, Kb, Vf, Yb);

  // out = y @ W_o^T : M=4096, N=2048, K=2048 -> 32x8 = 256 blocks
  gemmk32<false><<<(B_ * L_ / 128) * (D_ / 256), 512, 0, stream>>>(
      Yb, wob, out, B_ * L_, D_, D_);
}